// Round 7
// baseline (69.082 us; speedup 1.0000x reference)
//
#include <hip/hip_runtime.h>
#include <math.h>

// MultiHeadAttentionQuantum: analytic collapse of the 8-qubit circuit.
//   angles[t][n] = dot(x[t], w_q[n]) + q_params[n] ; c = cos(angles)
//   z[0] = c1..c7 ; z[w>=1] = c0..cw  (Heisenberg CNOT-ring push-through)
//   out[t][e] = sum_n z[n] * w_out[e][n]
//
// R7: R6 hit 43.5us but ran as ONE resident generation (2048 blocks = 8/CU,
// VGPR 64) -> lockstep load/compute/store phases, HBM duty only ~55%.
// Changes: (1) plain stores (no nt) so out lives in L3 alongside x
// (100+100 < 256 MB) and writeback is lazy/overlapped; (2) 2 tok/wave,
// grid 4096 -> two generations, turnover staggers phases.
// Envelope unchanged: bounds(256,4), no spill (VGPR <= 64 expected).

using f32x4 = __attribute__((ext_vector_type(4))) float;

constexpr int E  = 768;
constexpr int NW = 8;
constexpr int BLOCK = 256;                      // 4 waves
constexpr int TOKENS = 16 * 2048;               // 32768
constexpr int TOK_PER_WAVE  = 2;
constexpr int TOK_PER_BLOCK = TOK_PER_WAVE * 4; // 8
constexpr int GRID = TOKENS / TOK_PER_BLOCK;    // 4096

__device__ __forceinline__ float dot12(const f32x4& a0, const f32x4& a1, const f32x4& a2,
                                       const f32x4& b0, const f32x4& b1, const f32x4& b2) {
    return a0.x*b0.x + a0.y*b0.y + a0.z*b0.z + a0.w*b0.w
         + a1.x*b1.x + a1.y*b1.y + a1.z*b1.z + a1.w*b1.w
         + a2.x*b2.x + a2.y*b2.y + a2.z*b2.z + a2.w*b2.w;
}

// zf[n] = this lane's partial dot for wire n. Returns z[0..7] (broadcast to
// all lanes) after full-wave reduce + cos + CNOT-ring prefix products.
// Numerically verified R4-R6 (absmax 0.0078).
__device__ __forceinline__ void circuit8(const float zf[NW], int lane, float qpl,
                                         float z[NW]) {
    // multi-value butterfly: 10 shuffles, 10 adds
    float v4[4];
    #pragma unroll
    for (int i = 0; i < 4; ++i) {
        float a = zf[2*i], b = zf[2*i+1];
        float keep = (lane & 1) ? b : a;
        float send = (lane & 1) ? a : b;
        v4[i] = keep + __shfl_xor(send, 1, 64);
    }
    float v2[2];
    #pragma unroll
    for (int i = 0; i < 2; ++i) {
        float a = v4[2*i], b = v4[2*i+1];
        float keep = (lane & 2) ? b : a;
        float send = (lane & 2) ? a : b;
        v2[i] = keep + __shfl_xor(send, 2, 64);
    }
    float a = v2[0], b = v2[1];
    float keep = (lane & 4) ? b : a;
    float send = (lane & 4) ? a : b;
    float v = keep + __shfl_xor(send, 4, 64);
    v += __shfl_xor(v, 8, 64);
    v += __shfl_xor(v, 16, 64);
    v += __shfl_xor(v, 32, 64);
    // v = full angle for wire (lane&7); one cos per token
    float c = __cosf(v + qpl);
    // gather c0..c7 into every lane: 7 shuffles
    float cx = __shfl_xor(c, 1, 64);
    float e0 = (lane & 1) ? cx : c;
    float e1 = (lane & 1) ? c : cx;
    float e0x = __shfl_xor(e0, 2, 64), e1x = __shfl_xor(e1, 2, 64);
    float f0 = (lane & 2) ? e0x : e0;
    float f1 = (lane & 2) ? e1x : e1;
    float f2 = (lane & 2) ? e0  : e0x;
    float f3 = (lane & 2) ? e1  : e1x;
    float f0x = __shfl_xor(f0, 4, 64), f1x = __shfl_xor(f1, 4, 64);
    float f2x = __shfl_xor(f2, 4, 64), f3x = __shfl_xor(f3, 4, 64);
    float c0 = (lane & 4) ? f0x : f0;
    float c1 = (lane & 4) ? f1x : f1;
    float c2 = (lane & 4) ? f2x : f2;
    float c3 = (lane & 4) ? f3x : f3;
    float c4 = (lane & 4) ? f0  : f0x;
    float c5 = (lane & 4) ? f1  : f1x;
    float c6 = (lane & 4) ? f2  : f2x;
    float c7 = (lane & 4) ? f3  : f3x;
    // CNOT-ring push-through products
    float p1 = c0*c1, p2 = p1*c2, p3 = p2*c3, p4 = p3*c4;
    float p5 = p4*c5, p6 = p5*c6, p7 = p6*c7;
    float s  = c1*c2*c3*c4*c5*c6*c7;
    z[0] = s;  z[1] = p1; z[2] = p2; z[3] = p3;
    z[4] = p4; z[5] = p5; z[6] = p6; z[7] = p7;
}

__global__ __launch_bounds__(BLOCK, 4)
void mhaq_kernel(const float* __restrict__ x,
                 const float* __restrict__ w_q,
                 const float* __restrict__ w_out,
                 const float* __restrict__ q_params,
                 float* __restrict__ out)
{
    const int tid  = threadIdx.x;
    const int wave = tid >> 6;
    const int lane = tid & 63;
    const int col  = lane * 4;
    const int t0   = blockIdx.x * TOK_PER_BLOCK + wave * TOK_PER_WAVE;

    const float qpl = q_params[lane & 7];   // this lane's wire bias

    // ---- x loads: 2 tokens x 3 f32x4 per lane, coalesced, caching ----
    f32x4 xv[TOK_PER_WAVE][3];
    #pragma unroll
    for (int tt = 0; tt < TOK_PER_WAVE; ++tt) {
        const f32x4* xp = reinterpret_cast<const f32x4*>(x + (size_t)(t0 + tt) * E);
        #pragma unroll
        for (int k = 0; k < 3; ++k)
            xv[tt][k] = xp[lane + k * 64];
    }

    // ---- per-lane partial dots (w_q from L1/L2, coalesced) ----
    float zf[TOK_PER_WAVE][NW];
    #pragma unroll
    for (int n = 0; n < NW; ++n) {
        const f32x4* wp = reinterpret_cast<const f32x4*>(w_q + n * E + col);
        const f32x4 w0 = wp[0];
        const f32x4 w1 = wp[64];
        const f32x4 w2 = wp[128];
        #pragma unroll
        for (int tt = 0; tt < TOK_PER_WAVE; ++tt)
            zf[tt][n] = dot12(xv[tt][0], xv[tt][1], xv[tt][2], w0, w1, w2);
    }

    // ---- wave reduce + cos + prefix products ----
    float z[TOK_PER_WAVE][NW];
    #pragma unroll
    for (int tt = 0; tt < TOK_PER_WAVE; ++tt)
        circuit8(zf[tt], lane, qpl, z[tt]);

    // ---- epilogue: out[t][e] = sum_n z[n] * w_out[e][n], plain stores ----
    #pragma unroll
    for (int k = 0; k < 3; ++k) {
        const int e0 = k * 256 + col;          // this lane's 4 output columns
        f32x4 wa[4], wb[4];                    // w_out rows e0..e0+3
        #pragma unroll
        for (int e = 0; e < 4; ++e) {
            const f32x4* wp = reinterpret_cast<const f32x4*>(w_out + (size_t)(e0 + e) * NW);
            wa[e] = wp[0];
            wb[e] = wp[1];
        }
        #pragma unroll
        for (int tt = 0; tt < TOK_PER_WAVE; ++tt) {
            f32x4 o;
            #pragma unroll
            for (int e = 0; e < 4; ++e) {
                float v = z[tt][0] * wa[e].x + z[tt][1] * wa[e].y
                        + z[tt][2] * wa[e].z + z[tt][3] * wa[e].w
                        + z[tt][4] * wb[e].x + z[tt][5] * wb[e].y
                        + z[tt][6] * wb[e].z + z[tt][7] * wb[e].w;
                if (e == 0) o.x = v; else if (e == 1) o.y = v;
                else if (e == 2) o.z = v; else o.w = v;
            }
            *reinterpret_cast<f32x4*>(out + (size_t)(t0 + tt) * E + e0) = o;
        }
    }
}

extern "C" void kernel_launch(void* const* d_in, const int* in_sizes, int n_in,
                              void* d_out, int out_size, void* d_ws, size_t ws_size,
                              hipStream_t stream) {
    const float* x        = (const float*)d_in[0];
    const float* w_q      = (const float*)d_in[1];
    const float* w_out    = (const float*)d_in[2];
    const float* q_params = (const float*)d_in[3];
    float* out = (float*)d_out;

    hipLaunchKernelGGL(mhaq_kernel, dim3(GRID), dim3(BLOCK), 0, stream,
                       x, w_q, w_out, q_params, out);
}

// Round 8
// 37.175 us; speedup vs baseline: 1.8583x; 1.8583x over previous
//
#include <hip/hip_runtime.h>
#include <math.h>

// MultiHeadAttentionQuantum: analytic collapse of the 8-qubit circuit.
//   angles[t][n] = dot(x[t], w_q[n]) + q_params[n] ; c = cos(angles)
//   z[0] = c1..c7 ; z[w>=1] = c0..cw  (Heisenberg CNOT-ring push-through)
//   out[t][e] = sum_n z[n] * w_out[e][n]
//
// R8: R7 regression tracked per-token weight-VMEM, not store policy ->
// model: w_q+w_out (48 KB) thrash the 32 KB L1; every wave re-reads both
// matrices from L2 (393 MB aggregate). Fix: stage both weights in fp32 LDS
// (numerics identical to R6). Per-wave VMEM 72 -> 24 insts. LDS 48 KB ->
// 3 blocks/CU -> grid 2048 runs ~2.7 generations (stagger bonus).
// Everything else = R6 (best, 43.5us): 4 tok/wave, grid 2048, caching x
// loads, nt stores, circuit8 reduction.

using f32x4 = __attribute__((ext_vector_type(4))) float;

constexpr int E  = 768;
constexpr int NW = 8;
constexpr int BLOCK = 256;                      // 4 waves
constexpr int TOKENS = 16 * 2048;               // 32768
constexpr int TOK_PER_WAVE  = 4;
constexpr int TOK_PER_BLOCK = TOK_PER_WAVE * 4; // 16
constexpr int GRID = TOKENS / TOK_PER_BLOCK;    // 2048

__device__ __forceinline__ float dot12(const f32x4& a0, const f32x4& a1, const f32x4& a2,
                                       const f32x4& b0, const f32x4& b1, const f32x4& b2) {
    return a0.x*b0.x + a0.y*b0.y + a0.z*b0.z + a0.w*b0.w
         + a1.x*b1.x + a1.y*b1.y + a1.z*b1.z + a1.w*b1.w
         + a2.x*b2.x + a2.y*b2.y + a2.z*b2.z + a2.w*b2.w;
}

// Wave-wide reduce of zf[0..7] + cos + CNOT-ring prefix products.
// Numerically verified R4-R7 (absmax 0.0078).
__device__ __forceinline__ void circuit8(const float zf[NW], int lane, float qpl,
                                         float z[NW]) {
    float v4[4];
    #pragma unroll
    for (int i = 0; i < 4; ++i) {
        float a = zf[2*i], b = zf[2*i+1];
        float keep = (lane & 1) ? b : a;
        float send = (lane & 1) ? a : b;
        v4[i] = keep + __shfl_xor(send, 1, 64);
    }
    float v2[2];
    #pragma unroll
    for (int i = 0; i < 2; ++i) {
        float a = v4[2*i], b = v4[2*i+1];
        float keep = (lane & 2) ? b : a;
        float send = (lane & 2) ? a : b;
        v2[i] = keep + __shfl_xor(send, 2, 64);
    }
    float a = v2[0], b = v2[1];
    float keep = (lane & 4) ? b : a;
    float send = (lane & 4) ? a : b;
    float v = keep + __shfl_xor(send, 4, 64);
    v += __shfl_xor(v, 8, 64);
    v += __shfl_xor(v, 16, 64);
    v += __shfl_xor(v, 32, 64);
    float c = __cosf(v + qpl);               // one cos per token (wire lane&7)
    // gather c0..c7 into every lane: 7 shuffles
    float cx = __shfl_xor(c, 1, 64);
    float e0 = (lane & 1) ? cx : c;
    float e1 = (lane & 1) ? c : cx;
    float e0x = __shfl_xor(e0, 2, 64), e1x = __shfl_xor(e1, 2, 64);
    float f0 = (lane & 2) ? e0x : e0;
    float f1 = (lane & 2) ? e1x : e1;
    float f2 = (lane & 2) ? e0  : e0x;
    float f3 = (lane & 2) ? e1  : e1x;
    float f0x = __shfl_xor(f0, 4, 64), f1x = __shfl_xor(f1, 4, 64);
    float f2x = __shfl_xor(f2, 4, 64), f3x = __shfl_xor(f3, 4, 64);
    float c0 = (lane & 4) ? f0x : f0;
    float c1 = (lane & 4) ? f1x : f1;
    float c2 = (lane & 4) ? f2x : f2;
    float c3 = (lane & 4) ? f3x : f3;
    float c4 = (lane & 4) ? f0  : f0x;
    float c5 = (lane & 4) ? f1  : f1x;
    float c6 = (lane & 4) ? f2  : f2x;
    float c7 = (lane & 4) ? f3  : f3x;
    float p1 = c0*c1, p2 = p1*c2, p3 = p2*c3, p4 = p3*c4;
    float p5 = p4*c5, p6 = p5*c6, p7 = p6*c7;
    float s  = c1*c2*c3*c4*c5*c6*c7;
    z[0] = s;  z[1] = p1; z[2] = p2; z[3] = p3;
    z[4] = p4; z[5] = p5; z[6] = p6; z[7] = p7;
}

__global__ __launch_bounds__(BLOCK, 4)
void mhaq_kernel(const float* __restrict__ x,
                 const float* __restrict__ w_q,
                 const float* __restrict__ w_out,
                 const float* __restrict__ q_params,
                 float* __restrict__ out)
{
    __shared__ float wq_lds[NW][E];   // 24 KB, w_q as-is [n][e]
    __shared__ float wt_lds[NW][E];   // 24 KB, w_out transposed [n][e]

    const int tid  = threadIdx.x;
    const int wave = tid >> 6;
    const int lane = tid & 63;
    const int col  = lane * 4;
    const int t0   = blockIdx.x * TOK_PER_BLOCK + wave * TOK_PER_WAVE;

    // ---- stage weights once per block (L2-resident after first blocks) ----
    {
        const f32x4* src = reinterpret_cast<const f32x4*>(w_q);
        f32x4* dst = reinterpret_cast<f32x4*>(&wq_lds[0][0]);
        #pragma unroll
        for (int r = 0; r < (NW * E / 4) / BLOCK; ++r)
            dst[tid + r * BLOCK] = src[tid + r * BLOCK];
    }
    {
        const f32x4* src = reinterpret_cast<const f32x4*>(w_out);
        #pragma unroll
        for (int r = 0; r < (NW * E / 4) / BLOCK; ++r) {
            int idx = tid + r * BLOCK;       // f32x4 index into [768][8]
            f32x4 v = src[idx];
            int e  = idx >> 1;               // two f32x4 per e-row
            int n0 = (idx & 1) * 4;
            wt_lds[n0 + 0][e] = v.x;
            wt_lds[n0 + 1][e] = v.y;
            wt_lds[n0 + 2][e] = v.z;
            wt_lds[n0 + 3][e] = v.w;
        }
    }
    const float qpl = q_params[lane & 7];   // this lane's wire bias

    // ---- x loads issued BEFORE the barrier: overlap staging with HBM latency ----
    f32x4 xv[TOK_PER_WAVE][3];
    #pragma unroll
    for (int tt = 0; tt < TOK_PER_WAVE; ++tt) {
        const f32x4* xp = reinterpret_cast<const f32x4*>(x + (size_t)(t0 + tt) * E);
        #pragma unroll
        for (int k = 0; k < 3; ++k)
            xv[tt][k] = xp[lane + k * 64];
    }
    __syncthreads();

    // ---- per-lane partial dots (w_q from LDS) ----
    float zf[TOK_PER_WAVE][NW];
    #pragma unroll
    for (int n = 0; n < NW; ++n) {
        const f32x4 w0 = *reinterpret_cast<const f32x4*>(&wq_lds[n][col]);
        const f32x4 w1 = *reinterpret_cast<const f32x4*>(&wq_lds[n][col + 256]);
        const f32x4 w2 = *reinterpret_cast<const f32x4*>(&wq_lds[n][col + 512]);
        #pragma unroll
        for (int tt = 0; tt < TOK_PER_WAVE; ++tt)
            zf[tt][n] = dot12(xv[tt][0], xv[tt][1], xv[tt][2], w0, w1, w2);
    }

    // ---- wave reduce + cos + prefix products ----
    float z[TOK_PER_WAVE][NW];
    #pragma unroll
    for (int tt = 0; tt < TOK_PER_WAVE; ++tt)
        circuit8(zf[tt], lane, qpl, z[tt]);

    // ---- epilogue: out[t][e] = sum_n z[n] * w_out[e][n] (w_out from LDS) ----
    #pragma unroll
    for (int k = 0; k < 3; ++k) {
        const int e0 = k * 256 + col;
        f32x4 wv[NW];
        #pragma unroll
        for (int n = 0; n < NW; ++n)
            wv[n] = *reinterpret_cast<const f32x4*>(&wt_lds[n][e0]);
        #pragma unroll
        for (int tt = 0; tt < TOK_PER_WAVE; ++tt) {
            float ox = 0.f, oy = 0.f, oz = 0.f, ow = 0.f;
            #pragma unroll
            for (int n = 0; n < NW; ++n) {
                ox += z[tt][n] * wv[n].x;
                oy += z[tt][n] * wv[n].y;
                oz += z[tt][n] * wv[n].z;
                ow += z[tt][n] * wv[n].w;
            }
            f32x4 o; o.x = ox; o.y = oy; o.z = oz; o.w = ow;
            __builtin_nontemporal_store(
                o, reinterpret_cast<f32x4*>(out + (size_t)(t0 + tt) * E + e0));
        }
    }
}

extern "C" void kernel_launch(void* const* d_in, const int* in_sizes, int n_in,
                              void* d_out, int out_size, void* d_ws, size_t ws_size,
                              hipStream_t stream) {
    const float* x        = (const float*)d_in[0];
    const float* w_q      = (const float*)d_in[1];
    const float* w_out    = (const float*)d_in[2];
    const float* q_params = (const float*)d_in[3];
    float* out = (float*)d_out;

    hipLaunchKernelGGL(mhaq_kernel, dim3(GRID), dim3(BLOCK), 0, stream,
                       x, w_q, w_out, q_params, out);
}